// Round 5
// baseline (201.316 us; speedup 1.0000x reference)
//
#include <hip/hip_runtime.h>

typedef __attribute__((ext_vector_type(8))) __bf16 bf16x8;
typedef __attribute__((ext_vector_type(4))) __bf16 bf16x4;
typedef __attribute__((ext_vector_type(4))) float f32x4;

__device__ __forceinline__ void async_load16(const void* g, void* l) {
  __builtin_amdgcn_global_load_lds(
      (const __attribute__((address_space(1))) void*)g,
      (__attribute__((address_space(3))) void*)l, 16, 0, 0);
}

// ---------------- fp32 -> bf16 convert (vectorized) ----------------
__global__ void cvt_f32_bf16(const float* __restrict__ in,
                             __bf16* __restrict__ out, int n4) {
  int i = blockIdx.x * blockDim.x + threadIdx.x;
  int stride = gridDim.x * blockDim.x;
  for (; i < n4; i += stride) {
    float4 v = ((const float4*)in)[i];
    bf16x4 o;
    o[0] = (__bf16)v.x; o[1] = (__bf16)v.y; o[2] = (__bf16)v.z; o[3] = (__bf16)v.w;
    ((bf16x4*)out)[i] = o;
  }
}

// ---------------- C = (A @ Bm^T + bias) [*scale] ----------------
// MODE 0: fp32 out, row stride N.
// MODE 1 (QKV): cols<512 -> qk bf16 (scaled 0.125); 512..1023 -> qk bf16;
//               >=1024 -> vT[b*8+h][d][k] transposed bf16.
template <int MODE>
__global__ __launch_bounds__(256) void gemm_bt(
    const __bf16* __restrict__ A,   // [M][K]
    const __bf16* __restrict__ Bm,  // [N][K]
    const float* __restrict__ bias, // [N]
    void* __restrict__ C0,
    __bf16* __restrict__ vT,
    int M, int N, int K) {
  __shared__ __align__(16) char smem[32768];
  char* lA = smem;
  char* lB = smem + 16384;
  const int t = threadIdx.x;
  const int lane = t & 63;
  const int wid = t >> 6;
  const int wm = wid >> 1, wn = wid & 1;
  const int g = lane >> 4, ln = lane & 15;
  const int m0 = blockIdx.y * 128;
  const int n0 = blockIdx.x * 128;

  const int srow = t >> 3;
  const int sswz = ((t & 7) * 16) ^ ((srow & 7) << 4);
  const size_t KB = (size_t)K * 2;
  const char* gA = (const char*)A + (size_t)m0 * KB;
  const char* gB = (const char*)Bm + (size_t)n0 * KB;

  f32x4 acc[4][4] = {};

  for (int k0 = 0; k0 < K; k0 += 64) {
    __syncthreads();
#pragma unroll
    for (int c = 0; c < 4; ++c) {
      int row = srow + 32 * c;
      async_load16(gA + (size_t)row * KB + k0 * 2 + sswz, lA + c * 4096 + t * 16);
      async_load16(gB + (size_t)row * KB + k0 * 2 + sswz, lB + c * 4096 + t * 16);
    }
    __syncthreads();
#pragma unroll
    for (int ks = 0; ks < 2; ++ks) {
      bf16x8 af[4], bf[4];
#pragma unroll
      for (int i = 0; i < 4; ++i) {
        int ar = wm * 64 + i * 16 + ln;
        int byo = (ks * 64 + g * 16) ^ ((ar & 7) << 4);
        af[i] = *(const bf16x8*)(lA + ar * 128 + byo);
        int br = wn * 64 + i * 16 + ln;
        bf[i] = *(const bf16x8*)(lB + br * 128 + byo);
      }
#pragma unroll
      for (int i = 0; i < 4; ++i)
#pragma unroll
        for (int j = 0; j < 4; ++j)
          acc[i][j] = __builtin_amdgcn_mfma_f32_16x16x32_bf16(af[i], bf[j], acc[i][j], 0, 0, 0);
    }
  }

#pragma unroll
  for (int j = 0; j < 4; ++j) {
    int col = n0 + wn * 64 + j * 16 + ln;
    float bv = bias[col];
    if (MODE == 0) {
#pragma unroll
      for (int i = 0; i < 4; ++i) {
        int row0 = m0 + wm * 64 + i * 16 + g * 4;
#pragma unroll
        for (int r = 0; r < 4; ++r)
          ((float*)C0)[(size_t)(row0 + r) * N + col] = acc[i][j][r] + bv;
      }
    } else if (col < 1024) {
      float scale = (col < 512) ? 0.125f : 1.0f;
#pragma unroll
      for (int i = 0; i < 4; ++i) {
        int row0 = m0 + wm * 64 + i * 16 + g * 4;
#pragma unroll
        for (int r = 0; r < 4; ++r)
          ((__bf16*)C0)[(size_t)(row0 + r) * 1024 + col] = (__bf16)((acc[i][j][r] + bv) * scale);
      }
    } else {
      int h = (col - 1024) >> 6;
      int d = (col - 1024) & 63;
#pragma unroll
      for (int i = 0; i < 4; ++i) {
        int row0 = m0 + wm * 64 + i * 16 + g * 4;
        int b = row0 >> 10;
        bf16x4 pk;
#pragma unroll
        for (int r = 0; r < 4; ++r) pk[r] = (__bf16)(acc[i][j][r] + bv);
        *(bf16x4*)(vT + (((size_t)b * 8 + h) * 64 + d) * 1024 + (row0 & 1023)) = pk;
      }
    }
  }
}

// ---------------- fused flash attention: all-register K/V, zero barriers ----
// 512 blocks (XCD-swizzled), 512 threads = 8 waves = 8 heads. QT=16, KT=32.
// K/V/bias loaded straight to register fragments (compiler emits counted
// vmcnt waits); LDS only for the 1KB/wave P round-trip.
__global__ __launch_bounds__(512, 4) void attn_fused(
    const __bf16* __restrict__ qk,   // [B][N][1024]: q(prescaled)|k
    const __bf16* __restrict__ vT,   // [B*8][64 d][1024 k]
    const float* __restrict__ gbias, // [B][N][N]
    const float* __restrict__ bstr,  // [1]
    __bf16* __restrict__ attn) {     // [B][N][512]
  __shared__ __align__(16) char smem[8192];
  const int t = threadIdx.x;
  const int lane = t & 63;
  const int h = t >> 6;
  const int g = lane >> 4, ln = lane & 15;
  const int wg = ((blockIdx.x & 7) << 6) + (blockIdx.x >> 3);
  const int b = wg >> 6;
  const int q0 = (wg & 63) << 4;

  char* Ps = smem + h * 1024;  // [16 q][64B] swizzled P round-trip, wave-private

  const float alpha = 1.f / (1.f + __expf(-bstr[0]));
  const float bscale = 10.f * alpha;
  const f32x4 fzero = {0.f, 0.f, 0.f, 0.f};

  // Q A-frags: row = ln, k-dim = ks*32 + g*8 + j (prescaled by 1/8)
  bf16x8 qf[2];
#pragma unroll
  for (int ks = 0; ks < 2; ++ks)
    qf[ks] = *(const bf16x8*)(qk + ((size_t)b * 1024 + q0 + ln) * 1024 +
                              h * 64 + ks * 32 + g * 8);

  float m_run[4], l_run[4];
  f32x4 o_acc[4] = {};
#pragma unroll
  for (int r = 0; r < 4; ++r) { m_run[r] = -1e30f; l_run[r] = 0.f; }

  const char* qkb = (const char*)qk + (size_t)b * 1024 * 2048;
  const char* vTb = (const char*)vT + (size_t)(b * 8 + h) * 64 * 2048;
  const float* gbb = gbias + (size_t)b * 1024 * 1024 + q0;

  // K B-frags: kf[ni] row = 16ni+ln, d = ks*64B + g*16B within head
  // V B-frags: vf[di] row d = di*16+ln, k-slice = k0 + g*8
  bf16x8 kf[2][2], vf[4];
  float bcur[8];  // bias(cur tile): bcur[ni*4+r] for S[q=4g+r][k=16ni+ln]
  {
#pragma unroll
    for (int ni = 0; ni < 2; ++ni)
#pragma unroll
      for (int ks = 0; ks < 2; ++ks)
        kf[ni][ks] = *(const bf16x8*)(qkb + (size_t)(ni * 16 + ln) * 2048 +
                                      1024 + h * 128 + ks * 64 + g * 16);
#pragma unroll
    for (int di = 0; di < 4; ++di)
      vf[di] = *(const bf16x8*)(vTb + (size_t)(di * 16 + ln) * 2048 + g * 16);
#pragma unroll
    for (int ni = 0; ni < 2; ++ni)
#pragma unroll
      for (int r = 0; r < 4; ++r) {
        float v = gbb[(size_t)(ni * 16 + ln) * 1024 + g * 4 + r];
        bcur[ni * 4 + r] = bscale * (1.f / (1.f + __expf(-v)) - 0.5f);
      }
  }

  for (int kt = 0; kt < 32; ++kt) {
    const int k0n = (kt < 31) ? (kt + 1) * 32 : 0;  // wrapped (safe) prefetch

    // prefetch next tile's bias early (HBM ~900cy, used at loop end)
    float bnx[8];
#pragma unroll
    for (int ni = 0; ni < 2; ++ni)
#pragma unroll
      for (int r = 0; r < 4; ++r)
        bnx[ni * 4 + r] = gbb[(size_t)(k0n + ni * 16 + ln) * 1024 + g * 4 + r];

    // S = Q K^T  (D: q = 4g + r, key = ni*16 + ln); waits kf (counted vmcnt)
    f32x4 s[2];
#pragma unroll
    for (int ni = 0; ni < 2; ++ni) {
#pragma unroll
      for (int ks = 0; ks < 2; ++ks)
        s[ni] = __builtin_amdgcn_mfma_f32_16x16x32_bf16(
            qf[ks], kf[ni][ks], (ks == 0) ? fzero : s[ni], 0, 0, 0);
#pragma unroll
      for (int r = 0; r < 4; ++r)
        s[ni][r] += bcur[ni * 4 + r];
    }

    // reload K for next tile (covered by softmax+PV below)
#pragma unroll
    for (int ni = 0; ni < 2; ++ni)
#pragma unroll
      for (int ks = 0; ks < 2; ++ks)
        kf[ni][ks] = *(const bf16x8*)(qkb + (size_t)(k0n + ni * 16 + ln) * 2048 +
                                      1024 + h * 128 + ks * 64 + g * 16);

    // online softmax (rows spread over the 16 ln-lanes)
#pragma unroll
    for (int r = 0; r < 4; ++r) {
      float tm = fmaxf(s[0][r], s[1][r]);
#pragma unroll
      for (int off = 1; off < 16; off <<= 1)
        tm = fmaxf(tm, __shfl_xor(tm, off, 64));
      float newm = fmaxf(m_run[r], tm);
      float corr = __expf(m_run[r] - newm);
      float p0 = __expf(s[0][r] - newm);
      float p1 = __expf(s[1][r] - newm);
      s[0][r] = p0; s[1][r] = p1;
      float rs = p0 + p1;
#pragma unroll
      for (int off = 1; off < 16; off <<= 1)
        rs += __shfl_xor(rs, off, 64);
      m_run[r] = newm;
      l_run[r] = l_run[r] * corr + rs;
#pragma unroll
      for (int di = 0; di < 4; ++di)
        o_acc[di][r] *= corr;
    }

    // P -> LDS bf16 (swizzled, wave-private), read back as A-frag
#pragma unroll
    for (int ni = 0; ni < 2; ++ni)
#pragma unroll
      for (int r = 0; r < 4; ++r) {
        int q = g * 4 + r;
        *(__bf16*)(Ps + q * 64 + ((ni * 32 + ln * 2) ^ (((q >> 1) & 3) << 4))) =
            (__bf16)s[ni][r];
      }
    bf16x8 pf = *(const bf16x8*)(Ps + ln * 64 + ((g * 16) ^ (((ln >> 1) & 3) << 4)));

    // O += P V  (waits vf via counted vmcnt)
#pragma unroll
    for (int di = 0; di < 4; ++di)
      o_acc[di] = __builtin_amdgcn_mfma_f32_16x16x32_bf16(pf, vf[di], o_acc[di], 0, 0, 0);

    // reload V for next tile (covered by next QKT+softmax)
#pragma unroll
    for (int di = 0; di < 4; ++di)
      vf[di] = *(const bf16x8*)(vTb + (size_t)(di * 16 + ln) * 2048 + (size_t)k0n * 2 + g * 16);

    // convert prefetched bias (waits bnx here: ~full iteration of coverage)
#pragma unroll
    for (int i = 0; i < 8; ++i)
      bcur[i] = bscale * (1.f / (1.f + __expf(-bnx[i])) - 0.5f);
  }

  // normalize + store (attn[b][q][h*64 + di*16 + ln]); D row = 4g + r
#pragma unroll
  for (int r = 0; r < 4; ++r) {
    float inv = 1.f / l_run[r];
    int q = q0 + g * 4 + r;
#pragma unroll
    for (int di = 0; di < 4; ++di)
      attn[((size_t)b * 1024 + q) * 512 + h * 64 + di * 16 + ln] =
          (__bf16)(o_acc[di][r] * inv);
  }
}

extern "C" void kernel_launch(void* const* d_in, const int* in_sizes, int n_in,
                              void* d_out, int out_size, void* d_ws, size_t ws_size,
                              hipStream_t stream) {
  const float* x     = (const float*)d_in[0];
  const float* gb    = (const float*)d_in[1];
  const float* w_in  = (const float*)d_in[2];
  const float* b_in  = (const float*)d_in[3];
  const float* w_out = (const float*)d_in[4];
  const float* b_out = (const float*)d_in[5];
  const float* bstr  = (const float*)d_in[6];

  char* ws = (char*)d_ws;
  __bf16* qk  = (__bf16*)(ws);                        // 16777216 B
  __bf16* vT  = (__bf16*)(ws + 16777216);             // 8388608 B
  __bf16* xb  = (__bf16*)(ws + 25165824);             // 8388608 B
  __bf16* w1  = (__bf16*)(ws + 33554432);             // 1572864 B
  __bf16* w2  = (__bf16*)(ws + 35127296);             // 524288 B
  __bf16* attn_buf = xb;  // alias: x_bf16 dead after GEMM1

  cvt_f32_bf16<<<2048, 256, 0, stream>>>(x, xb, (8 * 1024 * 512) / 4);
  cvt_f32_bf16<<<768, 256, 0, stream>>>(w_in, w1, (1536 * 512) / 4);
  cvt_f32_bf16<<<256, 256, 0, stream>>>(w_out, w2, (512 * 512) / 4);

  gemm_bt<1><<<dim3(12, 64), 256, 0, stream>>>(xb, w1, b_in, qk, vT, 8192, 1536, 512);
  attn_fused<<<512, 512, 0, stream>>>(qk, vT, gb, bstr, attn_buf);
  gemm_bt<0><<<dim3(4, 64), 256, 0, stream>>>(attn_buf, w2, b_out, d_out, nullptr, 8192, 512, 512);
}

// Round 7
// 141.318 us; speedup vs baseline: 1.4246x; 1.4246x over previous
//
#include <hip/hip_runtime.h>

typedef __attribute__((ext_vector_type(8))) __bf16 bf16x8;
typedef __attribute__((ext_vector_type(4))) __bf16 bf16x4;
typedef __attribute__((ext_vector_type(4))) float f32x4;

#define LOG2E 1.44269504088896340736f

__device__ __forceinline__ void async_load16(const void* g, void* l) {
  __builtin_amdgcn_global_load_lds(
      (const __attribute__((address_space(1))) void*)g,
      (__attribute__((address_space(3))) void*)l, 16, 0, 0);
}

__device__ __forceinline__ float fast_exp2(float x) {
#if __has_builtin(__builtin_amdgcn_exp2f)
  return __builtin_amdgcn_exp2f(x);
#else
  return __expf(x * 0.6931471805599453f);
#endif
}

// ---------------- fp32 -> bf16 convert (vectorized) ----------------
__global__ void cvt_f32_bf16(const float* __restrict__ in,
                             __bf16* __restrict__ out, int n4) {
  int i = blockIdx.x * blockDim.x + threadIdx.x;
  int stride = gridDim.x * blockDim.x;
  for (; i < n4; i += stride) {
    float4 v = ((const float4*)in)[i];
    bf16x4 o;
    o[0] = (__bf16)v.x; o[1] = (__bf16)v.y; o[2] = (__bf16)v.z; o[3] = (__bf16)v.w;
    ((bf16x4*)out)[i] = o;
  }
}

// ---------------- C = (A @ Bm^T + bias) [*scale] ----------------
// MODE 0: fp32 out. MODE 1: cols<512 -> qk bf16 scaled 0.125*log2e (log2-domain
// Q); 512..1023 -> qk bf16; >=1024 -> vT[b*8+h][d][k] transposed bf16.
template <int MODE>
__global__ __launch_bounds__(256) void gemm_bt(
    const __bf16* __restrict__ A, const __bf16* __restrict__ Bm,
    const float* __restrict__ bias, void* __restrict__ C0,
    __bf16* __restrict__ vT, int M, int N, int K) {
  __shared__ __align__(16) char smem[32768];
  char* lA = smem;
  char* lB = smem + 16384;
  const int t = threadIdx.x;
  const int lane = t & 63;
  const int wid = t >> 6;
  const int wm = wid >> 1, wn = wid & 1;
  const int g = lane >> 4, ln = lane & 15;
  const int m0 = blockIdx.y * 128;
  const int n0 = blockIdx.x * 128;

  const int srow = t >> 3;
  const int sswz = ((t & 7) * 16) ^ ((srow & 7) << 4);
  const size_t KB = (size_t)K * 2;
  const char* gA = (const char*)A + (size_t)m0 * KB;
  const char* gB = (const char*)Bm + (size_t)n0 * KB;

  f32x4 acc[4][4] = {};

  for (int k0 = 0; k0 < K; k0 += 64) {
    __syncthreads();
#pragma unroll
    for (int c = 0; c < 4; ++c) {
      int row = srow + 32 * c;
      async_load16(gA + (size_t)row * KB + k0 * 2 + sswz, lA + c * 4096 + t * 16);
      async_load16(gB + (size_t)row * KB + k0 * 2 + sswz, lB + c * 4096 + t * 16);
    }
    __syncthreads();
#pragma unroll
    for (int ks = 0; ks < 2; ++ks) {
      bf16x8 af[4], bf[4];
#pragma unroll
      for (int i = 0; i < 4; ++i) {
        int ar = wm * 64 + i * 16 + ln;
        int byo = (ks * 64 + g * 16) ^ ((ar & 7) << 4);
        af[i] = *(const bf16x8*)(lA + ar * 128 + byo);
        int br = wn * 64 + i * 16 + ln;
        bf[i] = *(const bf16x8*)(lB + br * 128 + byo);
      }
#pragma unroll
      for (int i = 0; i < 4; ++i)
#pragma unroll
        for (int j = 0; j < 4; ++j)
          acc[i][j] = __builtin_amdgcn_mfma_f32_16x16x32_bf16(af[i], bf[j], acc[i][j], 0, 0, 0);
    }
  }

#pragma unroll
  for (int j = 0; j < 4; ++j) {
    int col = n0 + wn * 64 + j * 16 + ln;
    float bv = bias[col];
    if (MODE == 0) {
#pragma unroll
      for (int i = 0; i < 4; ++i) {
        int row0 = m0 + wm * 64 + i * 16 + g * 4;
#pragma unroll
        for (int r = 0; r < 4; ++r)
          ((float*)C0)[(size_t)(row0 + r) * N + col] = acc[i][j][r] + bv;
      }
    } else if (col < 1024) {
      float scale = (col < 512) ? (0.125f * LOG2E) : 1.0f;
#pragma unroll
      for (int i = 0; i < 4; ++i) {
        int row0 = m0 + wm * 64 + i * 16 + g * 4;
#pragma unroll
        for (int r = 0; r < 4; ++r)
          ((__bf16*)C0)[(size_t)(row0 + r) * 1024 + col] = (__bf16)((acc[i][j][r] + bv) * scale);
      }
    } else {
      int h = (col - 1024) >> 6;
      int d = (col - 1024) & 63;
#pragma unroll
      for (int i = 0; i < 4; ++i) {
        int row0 = m0 + wm * 64 + i * 16 + g * 4;
        int b = row0 >> 10;
        bf16x4 pk;
#pragma unroll
        for (int r = 0; r < 4; ++r) pk[r] = (__bf16)(acc[i][j][r] + bv);
        *(bf16x4*)(vT + (((size_t)b * 8 + h) * 64 + d) * 1024 + (row0 & 1023)) = pk;
      }
    }
  }
}

// ---------------- fused flash attention: no-max log2 softmax --------------
// R4 transport (validated): stage K/V at loop end, single vmcnt(0) at loop
// top, wave-private LDS, zero barriers. 512 blocks (XCD-swizzled), 8 waves =
// 8 heads, QT=16, KT=32. p = 2^(qk*log2e/8 + bias*log2e), no max subtraction
// (scores bounded); bias via MFMA C-operand; l reduced once at the end.
__global__ __launch_bounds__(512, 4) void attn_fused(
    const __bf16* __restrict__ qk,   // [B][N][1024]: q(log2-prescaled)|k
    const __bf16* __restrict__ vT,   // [B*8][64 d][1024 k]
    const float* __restrict__ gbias, // [B][N][N]
    const float* __restrict__ bstr,  // [1]
    __bf16* __restrict__ attn) {     // [B][N][512]
  __shared__ __align__(16) char smem[73728];
  const int t = threadIdx.x;
  const int lane = t & 63;
  const int h = t >> 6;
  const int g = lane >> 4, ln = lane & 15;
  const int wg = ((blockIdx.x & 7) << 6) + (blockIdx.x >> 3);
  const int b = wg >> 6;
  const int q0 = (wg & 63) << 4;

  char* Ks = smem + h * 9216;  // [32 k][128B] swizzled (wave-private)
  char* Vs = Ks + 4096;        // [64 d][64B] swizzled (wave-private)
  char* Ps = Ks + 8192;        // [16 q][64B] P round-trip (separate region)

  const float alpha = 1.f / (1.f + __expf(-bstr[0]));
  const float bsc = 10.f * alpha * LOG2E;

  // Q A-frags: row = ln, k-dim = ks*32 + g*8 + j (prescaled by log2e/8)
  bf16x8 qf[2];
#pragma unroll
  for (int ks = 0; ks < 2; ++ks)
    qf[ks] = *(const bf16x8*)(qk + ((size_t)b * 1024 + q0 + ln) * 1024 +
                              h * 64 + ks * 32 + g * 8);

  float l_acc[4] = {0.f, 0.f, 0.f, 0.f};
  f32x4 o_acc[4] = {};

  const int krow = lane >> 3;
  const int ksrc = ((lane & 7) * 16) ^ (krow << 4);
  const int vrow = lane >> 2;
  const int vsrc = ((lane & 3) * 16) ^ ((vrow & 3) << 4);

  const char* qkb = (const char*)qk + (size_t)b * 1024 * 2048;
  const char* vTb = (const char*)vT + (size_t)(b * 8 + h) * 64 * 2048;
  const float* gbb = gbias + (size_t)b * 1024 * 1024 + q0;

  // bias register prefetch, two tiles deep: bp_a = tile 0, bp_b = tile 1
  // bp[ni*4+r] = gbias[b][k0+16ni+ln][q0+4g+r]
  float bp_a[8], bp_b[8];
#pragma unroll
  for (int ni = 0; ni < 2; ++ni)
#pragma unroll
    for (int r = 0; r < 4; ++r) {
      bp_a[ni * 4 + r] = gbb[(size_t)(ni * 16 + ln) * 1024 + g * 4 + r];
      bp_b[ni * 4 + r] = gbb[(size_t)(32 + ni * 16 + ln) * 1024 + g * 4 + r];
    }

  // stage tile 0 (wave-private K/V)
#pragma unroll
  for (int c = 0; c < 4; ++c) {
    async_load16(qkb + (size_t)(c * 8 + krow) * 2048 + 1024 + h * 128 + ksrc,
                 Ks + c * 1024 + lane * 16);
    async_load16(vTb + (size_t)(c * 16 + vrow) * 2048 + vsrc,
                 Vs + c * 1024 + lane * 16);
  }

  for (int kt = 0; kt < 32; ++kt) {
    const int k1 = ((kt < 31) ? kt + 1 : 0) * 32;  // next K/V tile (wrapped)
    const int k2 = ((kt < 30) ? kt + 2 : 0) * 32;  // bias 2-ahead (wrapped)

    // drain: K/V(t) staged last iter, bias(t),(t+1) loaded >=1 iter ago
    asm volatile("s_waitcnt vmcnt(0)" ::: "memory");
    __builtin_amdgcn_sched_barrier(0);

    // bias(t) -> log2-domain C-operands; rotate; issue bias(t+2) loads
    f32x4 lbf0, lbf1;
#pragma unroll
    for (int r = 0; r < 4; ++r) {
      lbf0[r] = bsc * (1.f / (1.f + __expf(-bp_a[r])) - 0.5f);
      lbf1[r] = bsc * (1.f / (1.f + __expf(-bp_a[4 + r])) - 0.5f);
    }
#pragma unroll
    for (int i = 0; i < 8; ++i) bp_a[i] = bp_b[i];
#pragma unroll
    for (int ni = 0; ni < 2; ++ni)
#pragma unroll
      for (int r = 0; r < 4; ++r)
        bp_b[ni * 4 + r] = gbb[(size_t)(k2 + ni * 16 + ln) * 1024 + g * 4 + r];

    // K frag reads (tile t)
    bf16x8 kf[2][2];
#pragma unroll
    for (int ni = 0; ni < 2; ++ni) {
      int br = ni * 16 + ln;
      int sw = (br & 7) << 4;
#pragma unroll
      for (int ks = 0; ks < 2; ++ks)
        kf[ni][ks] = *(const bf16x8*)(Ks + br * 128 + ((ks * 64 + g * 16) ^ sw));
    }
    asm volatile("s_waitcnt lgkmcnt(0)" ::: "memory");
    __builtin_amdgcn_sched_barrier(0);
    // stage K(t+1): kf data already in VGPRs
#pragma unroll
    for (int c = 0; c < 4; ++c)
      async_load16(qkb + (size_t)(k1 + c * 8 + krow) * 2048 + 1024 + h * 128 + ksrc,
                   Ks + c * 1024 + lane * 16);
    __builtin_amdgcn_sched_barrier(0);

    // S = QK^T + bias via C-operand (D: q = 4g + r, key = ni*16 + ln)
    f32x4 s[2];
    s[0] = __builtin_amdgcn_mfma_f32_16x16x32_bf16(qf[0], kf[0][0], lbf0, 0, 0, 0);
    s[0] = __builtin_amdgcn_mfma_f32_16x16x32_bf16(qf[1], kf[0][1], s[0], 0, 0, 0);
    s[1] = __builtin_amdgcn_mfma_f32_16x16x32_bf16(qf[0], kf[1][0], lbf1, 0, 0, 0);
    s[1] = __builtin_amdgcn_mfma_f32_16x16x32_bf16(qf[1], kf[1][1], s[1], 0, 0, 0);

    // p = 2^s (no max subtraction); accumulate l; P round-trip through LDS
#pragma unroll
    for (int r = 0; r < 4; ++r) {
      float p0 = fast_exp2(s[0][r]);
      float p1 = fast_exp2(s[1][r]);
      s[0][r] = p0; s[1][r] = p1;
      l_acc[r] += p0 + p1;
    }
#pragma unroll
    for (int ni = 0; ni < 2; ++ni)
#pragma unroll
      for (int r = 0; r < 4; ++r) {
        int q = g * 4 + r;
        *(__bf16*)(Ps + q * 64 + ((ni * 32 + ln * 2) ^ (((q >> 1) & 3) << 4))) =
            (__bf16)s[ni][r];
      }
    bf16x8 pf = *(const bf16x8*)(Ps + ln * 64 + ((g * 16) ^ (((ln >> 1) & 3) << 4)));

    // V frag reads (tile t)
    bf16x8 vf[4];
#pragma unroll
    for (int di = 0; di < 4; ++di)
      vf[di] = *(const bf16x8*)(Vs + (di * 16 + ln) * 64 + ((g * 16) ^ ((ln & 3) << 4)));
    asm volatile("s_waitcnt lgkmcnt(0)" ::: "memory");
    __builtin_amdgcn_sched_barrier(0);
    // stage V(t+1): vf data already in VGPRs
#pragma unroll
    for (int c = 0; c < 4; ++c)
      async_load16(vTb + (size_t)(c * 16 + vrow) * 2048 + (size_t)k1 * 2 + vsrc,
                   Vs + c * 1024 + lane * 16);
    __builtin_amdgcn_sched_barrier(0);

    // O += P V
#pragma unroll
    for (int di = 0; di < 4; ++di)
      o_acc[di] = __builtin_amdgcn_mfma_f32_16x16x32_bf16(pf, vf[di], o_acc[di], 0, 0, 0);
  }

  // reduce l over the 16 ln-lanes (butterfly), normalize, store
#pragma unroll
  for (int r = 0; r < 4; ++r) {
    float rs = l_acc[r];
#pragma unroll
    for (int off = 1; off < 16; off <<= 1)
      rs += __shfl_xor(rs, off, 64);
    float inv = 1.f / rs;
    int q = q0 + g * 4 + r;
#pragma unroll
    for (int di = 0; di < 4; ++di)
      attn[((size_t)b * 1024 + q) * 512 + h * 64 + di * 16 + ln] =
          (__bf16)(o_acc[di][r] * inv);
  }
}

extern "C" void kernel_launch(void* const* d_in, const int* in_sizes, int n_in,
                              void* d_out, int out_size, void* d_ws, size_t ws_size,
                              hipStream_t stream) {
  const float* x     = (const float*)d_in[0];
  const float* gb    = (const float*)d_in[1];
  const float* w_in  = (const float*)d_in[2];
  const float* b_in  = (const float*)d_in[3];
  const float* w_out = (const float*)d_in[4];
  const float* b_out = (const float*)d_in[5];
  const float* bstr  = (const float*)d_in[6];

  char* ws = (char*)d_ws;
  __bf16* qk  = (__bf16*)(ws);                        // 16,777,216 B
  __bf16* vT  = (__bf16*)(ws + 16777216);             //  8,388,608 B
  __bf16* xb  = (__bf16*)(ws + 25165824);             //  8,388,608 B
  __bf16* w1  = (__bf16*)(ws + 33554432);             //  1,572,864 B
  __bf16* w2  = (__bf16*)(ws + 35127296);             //    524,288 B (35.7MB tot)
  __bf16* attn_buf = xb;  // alias: x_bf16 dead after GEMM1

  cvt_f32_bf16<<<2048, 256, 0, stream>>>(x, xb, (8 * 1024 * 512) / 4);
  cvt_f32_bf16<<<768, 256, 0, stream>>>(w_in, w1, (1536 * 512) / 4);
  cvt_f32_bf16<<<256, 256, 0, stream>>>(w_out, w2, (512 * 512) / 4);

  gemm_bt<1><<<dim3(12, 64), 256, 0, stream>>>(xb, w1, b_in, qk, vT, 8192, 1536, 512);
  attn_fused<<<512, 512, 0, stream>>>(qk, vT, gb, bstr, attn_buf);
  gemm_bt<0><<<dim3(4, 64), 256, 0, stream>>>(attn_buf, w2, b_out, d_out, nullptr, 8192, 512, 512);
}

// Round 8
// 123.927 us; speedup vs baseline: 1.6245x; 1.1403x over previous
//
#include <hip/hip_runtime.h>

typedef __attribute__((ext_vector_type(8))) __bf16 bf16x8;
typedef __attribute__((ext_vector_type(4))) __bf16 bf16x4;
typedef __attribute__((ext_vector_type(4))) float f32x4;
typedef __attribute__((ext_vector_type(8))) _Float16 f16x8;

#define LOG2E 1.44269504088896340736f

__device__ __forceinline__ void async_load16(const void* g, void* l) {
  __builtin_amdgcn_global_load_lds(
      (const __attribute__((address_space(1))) void*)g,
      (__attribute__((address_space(3))) void*)l, 16, 0, 0);
}

__device__ __forceinline__ float fast_exp2(float x) {
#if __has_builtin(__builtin_amdgcn_exp2f)
  return __builtin_amdgcn_exp2f(x);
#else
  return __expf(x * 0.6931471805599453f);
#endif
}

// ---------------- fp32 -> bf16 convert (vectorized) ----------------
__global__ void cvt_f32_bf16(const float* __restrict__ in,
                             __bf16* __restrict__ out, int n4) {
  int i = blockIdx.x * blockDim.x + threadIdx.x;
  int stride = gridDim.x * blockDim.x;
  for (; i < n4; i += stride) {
    float4 v = ((const float4*)in)[i];
    bf16x4 o;
    o[0] = (__bf16)v.x; o[1] = (__bf16)v.y; o[2] = (__bf16)v.z; o[3] = (__bf16)v.w;
    ((bf16x4*)out)[i] = o;
  }
}

// ---------------- log2-domain bias table, per-lane fragment layout ----------
// ebT f16x8 index (((b*64+qt)*32+kt)*64 + lane); element [ni*4+r] =
//   (sigmoid(gbias[b][kt*32+16ni+ln][qt*16+4g+r]) - 0.5) * 10*alpha*log2e
__global__ __launch_bounds__(256) void build_ebias(
    const float* __restrict__ gbias, const float* __restrict__ bstr,
    _Float16* __restrict__ ebT) {
  const int gid = blockIdx.x * 256 + threadIdx.x;  // 4096 blocks
  const int lane = gid & 63;
  const int kt = (gid >> 6) & 31;
  const int qt = (gid >> 11) & 63;
  const int b = gid >> 17;
  const int g = lane >> 4, ln = lane & 15;
  const float alpha = 1.f / (1.f + __expf(-bstr[0]));
  const float bsc = 10.f * alpha * LOG2E;
  f16x8 o;
#pragma unroll
  for (int ni = 0; ni < 2; ++ni)
#pragma unroll
    for (int r = 0; r < 4; ++r) {
      float gv = gbias[(size_t)(b * 1024 + kt * 32 + ni * 16 + ln) * 1024 +
                       qt * 16 + g * 4 + r];
      float sg = 1.f / (1.f + __expf(-gv));
      o[ni * 4 + r] = (_Float16)((sg - 0.5f) * bsc);
    }
  *(f16x8*)(ebT + (size_t)gid * 8) = o;
}

// ---------------- C = (A @ Bm^T + bias) [*scale] ----------------
template <int MODE>
__global__ __launch_bounds__(256) void gemm_bt(
    const __bf16* __restrict__ A, const __bf16* __restrict__ Bm,
    const float* __restrict__ bias, void* __restrict__ C0,
    __bf16* __restrict__ vT, int M, int N, int K) {
  __shared__ __align__(16) char smem[32768];
  char* lA = smem;
  char* lB = smem + 16384;
  const int t = threadIdx.x;
  const int lane = t & 63;
  const int wid = t >> 6;
  const int wm = wid >> 1, wn = wid & 1;
  const int g = lane >> 4, ln = lane & 15;
  const int m0 = blockIdx.y * 128;
  const int n0 = blockIdx.x * 128;

  const int srow = t >> 3;
  const int sswz = ((t & 7) * 16) ^ ((srow & 7) << 4);
  const size_t KB = (size_t)K * 2;
  const char* gA = (const char*)A + (size_t)m0 * KB;
  const char* gB = (const char*)Bm + (size_t)n0 * KB;

  f32x4 acc[4][4] = {};

  for (int k0 = 0; k0 < K; k0 += 64) {
    __syncthreads();
#pragma unroll
    for (int c = 0; c < 4; ++c) {
      int row = srow + 32 * c;
      async_load16(gA + (size_t)row * KB + k0 * 2 + sswz, lA + c * 4096 + t * 16);
      async_load16(gB + (size_t)row * KB + k0 * 2 + sswz, lB + c * 4096 + t * 16);
    }
    __syncthreads();
#pragma unroll
    for (int ks = 0; ks < 2; ++ks) {
      bf16x8 af[4], bf[4];
#pragma unroll
      for (int i = 0; i < 4; ++i) {
        int ar = wm * 64 + i * 16 + ln;
        int byo = (ks * 64 + g * 16) ^ ((ar & 7) << 4);
        af[i] = *(const bf16x8*)(lA + ar * 128 + byo);
        int br = wn * 64 + i * 16 + ln;
        bf[i] = *(const bf16x8*)(lB + br * 128 + byo);
      }
#pragma unroll
      for (int i = 0; i < 4; ++i)
#pragma unroll
        for (int j = 0; j < 4; ++j)
          acc[i][j] = __builtin_amdgcn_mfma_f32_16x16x32_bf16(af[i], bf[j], acc[i][j], 0, 0, 0);
    }
  }

#pragma unroll
  for (int j = 0; j < 4; ++j) {
    int col = n0 + wn * 64 + j * 16 + ln;
    float bv = bias[col];
    if (MODE == 0) {
#pragma unroll
      for (int i = 0; i < 4; ++i) {
        int row0 = m0 + wm * 64 + i * 16 + g * 4;
#pragma unroll
        for (int r = 0; r < 4; ++r)
          ((float*)C0)[(size_t)(row0 + r) * N + col] = acc[i][j][r] + bv;
      }
    } else if (col < 1024) {
      float scale = (col < 512) ? (0.125f * LOG2E) : 1.0f;
#pragma unroll
      for (int i = 0; i < 4; ++i) {
        int row0 = m0 + wm * 64 + i * 16 + g * 4;
#pragma unroll
        for (int r = 0; r < 4; ++r)
          ((__bf16*)C0)[(size_t)(row0 + r) * 1024 + col] = (__bf16)((acc[i][j][r] + bv) * scale);
      }
    } else {
      int h = (col - 1024) >> 6;
      int d = (col - 1024) & 63;
#pragma unroll
      for (int i = 0; i < 4; ++i) {
        int row0 = m0 + wm * 64 + i * 16 + g * 4;
        int b = row0 >> 10;
        bf16x4 pk;
#pragma unroll
        for (int r = 0; r < 4; ++r) pk[r] = (__bf16)(acc[i][j][r] + bv);
        *(bf16x4*)(vT + (((size_t)b * 8 + h) * 64 + d) * 1024 + (row0 & 1023)) = pk;
      }
    }
  }
}

// ---------------- fused flash attention: no-max log2 softmax --------------
// R7 transport: stage at loop end... except V staging HOISTED before the S
// compute so its latency is covered by S/softmax/P (~500cy) instead of only
// the PV MFMAs. TABLE=1: bias from precomputed f16 table (1 coalesced 16B
// load/iter, no sigmoid); TABLE=0: R7 sigmoid path (2-deep prefetch).
template <int TABLE>
__global__ __launch_bounds__(512, 4) void attn_fused(
    const __bf16* __restrict__ qk,    // [B][N][1024]: q(log2-prescaled)|k
    const __bf16* __restrict__ vT,    // [B*8][64 d][1024 k]
    const _Float16* __restrict__ ebT, // f16 bias table (TABLE=1)
    const float* __restrict__ gbias,  // [B][N][N]    (TABLE=0)
    const float* __restrict__ bstr,   // [1]
    __bf16* __restrict__ attn) {      // [B][N][512]
  __shared__ __align__(16) char smem[73728];
  const int t = threadIdx.x;
  const int lane = t & 63;
  const int h = t >> 6;
  const int g = lane >> 4, ln = lane & 15;
  const int wg = ((blockIdx.x & 7) << 6) + (blockIdx.x >> 3);
  const int b = wg >> 6;
  const int q0 = (wg & 63) << 4;

  char* Ks = smem + h * 9216;  // [32 k][128B] swizzled (wave-private)
  char* Vs = Ks + 4096;        // [64 d][64B] swizzled (wave-private)
  char* Ps = Ks + 8192;        // [16 q][64B] P round-trip

  const float alpha = 1.f / (1.f + __expf(-bstr[0]));
  const float bsc = 10.f * alpha * LOG2E;

  bf16x8 qf[2];
#pragma unroll
  for (int ks = 0; ks < 2; ++ks)
    qf[ks] = *(const bf16x8*)(qk + ((size_t)b * 1024 + q0 + ln) * 1024 +
                              h * 64 + ks * 32 + g * 8);

  float l_acc[4] = {0.f, 0.f, 0.f, 0.f};
  f32x4 o_acc[4] = {};

  const int krow = lane >> 3;
  const int ksrc = ((lane & 7) * 16) ^ (krow << 4);
  const int vrow = lane >> 2;
  const int vsrc = ((lane & 3) * 16) ^ ((vrow & 3) << 4);

  const char* qkb = (const char*)qk + (size_t)b * 1024 * 2048;
  const char* vTb = (const char*)vT + (size_t)(b * 8 + h) * 64 * 2048;
  const float* gbb = gbias + (size_t)b * 1024 * 1024 + q0;
  const _Float16* ebp = ebT + (size_t)((b * 64 + (wg & 63)) * 32) * 512 + lane * 8;

  // bias state: TABLE=1 -> ebc holds tile t; TABLE=0 -> bp_a/bp_b 2-deep
  f16x8 ebc = {}, ebn = {};
  float bp_a[8], bp_b[8];
  if (TABLE) {
    ebc = *(const f16x8*)(ebp);
  } else {
#pragma unroll
    for (int ni = 0; ni < 2; ++ni)
#pragma unroll
      for (int r = 0; r < 4; ++r) {
        bp_a[ni * 4 + r] = gbb[(size_t)(ni * 16 + ln) * 1024 + g * 4 + r];
        bp_b[ni * 4 + r] = gbb[(size_t)(32 + ni * 16 + ln) * 1024 + g * 4 + r];
      }
  }

  // stage tile 0
#pragma unroll
  for (int c = 0; c < 4; ++c) {
    async_load16(qkb + (size_t)(c * 8 + krow) * 2048 + 1024 + h * 128 + ksrc,
                 Ks + c * 1024 + lane * 16);
    async_load16(vTb + (size_t)(c * 16 + vrow) * 2048 + vsrc,
                 Vs + c * 1024 + lane * 16);
  }

  for (int kt = 0; kt < 32; ++kt) {
    const int k1 = ((kt < 31) ? kt + 1 : 0) * 32;
    const int k2 = ((kt < 30) ? kt + 2 : 0) * 32;

    // drain: K/V(t) staged last iter (full-iter coverage), bias loads ready
    asm volatile("s_waitcnt vmcnt(0)" ::: "memory");
    __builtin_amdgcn_sched_barrier(0);

    // bias(t) -> C-operands; issue next bias load(s)
    f32x4 lbf0, lbf1;
    if (TABLE) {
      lbf0[0] = (float)ebc[0]; lbf0[1] = (float)ebc[1];
      lbf0[2] = (float)ebc[2]; lbf0[3] = (float)ebc[3];
      lbf1[0] = (float)ebc[4]; lbf1[1] = (float)ebc[5];
      lbf1[2] = (float)ebc[6]; lbf1[3] = (float)ebc[7];
      ebn = *(const f16x8*)(ebp + (size_t)(k1 >> 5) * 512);
    } else {
#pragma unroll
      for (int r = 0; r < 4; ++r) {
        lbf0[r] = bsc * (1.f / (1.f + __expf(-bp_a[r])) - 0.5f);
        lbf1[r] = bsc * (1.f / (1.f + __expf(-bp_a[4 + r])) - 0.5f);
      }
#pragma unroll
      for (int i = 0; i < 8; ++i) bp_a[i] = bp_b[i];
#pragma unroll
      for (int ni = 0; ni < 2; ++ni)
#pragma unroll
        for (int r = 0; r < 4; ++r)
          bp_b[ni * 4 + r] = gbb[(size_t)(k2 + ni * 16 + ln) * 1024 + g * 4 + r];
    }

    // K frag reads (t), then stage K(t+1)
    bf16x8 kf[2][2];
#pragma unroll
    for (int ni = 0; ni < 2; ++ni) {
      int br = ni * 16 + ln;
      int sw = (br & 7) << 4;
#pragma unroll
      for (int ks = 0; ks < 2; ++ks)
        kf[ni][ks] = *(const bf16x8*)(Ks + br * 128 + ((ks * 64 + g * 16) ^ sw));
    }
    asm volatile("s_waitcnt lgkmcnt(0)" ::: "memory");
    __builtin_amdgcn_sched_barrier(0);
#pragma unroll
    for (int c = 0; c < 4; ++c)
      async_load16(qkb + (size_t)(k1 + c * 8 + krow) * 2048 + 1024 + h * 128 + ksrc,
                   Ks + c * 1024 + lane * 16);
    __builtin_amdgcn_sched_barrier(0);

    // V frag reads (t), then stage V(t+1)  [HOISTED: covered by S+softmax+P]
    bf16x8 vf[4];
#pragma unroll
    for (int di = 0; di < 4; ++di)
      vf[di] = *(const bf16x8*)(Vs + (di * 16 + ln) * 64 + ((g * 16) ^ ((ln & 3) << 4)));
    asm volatile("s_waitcnt lgkmcnt(0)" ::: "memory");
    __builtin_amdgcn_sched_barrier(0);
#pragma unroll
    for (int c = 0; c < 4; ++c)
      async_load16(vTb + (size_t)(c * 16 + vrow) * 2048 + (size_t)k1 * 2 + vsrc,
                   Vs + c * 1024 + lane * 16);
    __builtin_amdgcn_sched_barrier(0);

    // S = QK^T + bias via C-operand (D: q = 4g + r, key = ni*16 + ln)
    f32x4 s[2];
    s[0] = __builtin_amdgcn_mfma_f32_16x16x32_bf16(qf[0], kf[0][0], lbf0, 0, 0, 0);
    s[0] = __builtin_amdgcn_mfma_f32_16x16x32_bf16(qf[1], kf[0][1], s[0], 0, 0, 0);
    s[1] = __builtin_amdgcn_mfma_f32_16x16x32_bf16(qf[0], kf[1][0], lbf1, 0, 0, 0);
    s[1] = __builtin_amdgcn_mfma_f32_16x16x32_bf16(qf[1], kf[1][1], s[1], 0, 0, 0);

    // p = 2^s; accumulate l; P round-trip through LDS
#pragma unroll
    for (int r = 0; r < 4; ++r) {
      float p0 = fast_exp2(s[0][r]);
      float p1 = fast_exp2(s[1][r]);
      s[0][r] = p0; s[1][r] = p1;
      l_acc[r] += p0 + p1;
    }
#pragma unroll
    for (int ni = 0; ni < 2; ++ni)
#pragma unroll
      for (int r = 0; r < 4; ++r) {
        int q = g * 4 + r;
        *(__bf16*)(Ps + q * 64 + ((ni * 32 + ln * 2) ^ (((q >> 1) & 3) << 4))) =
            (__bf16)s[ni][r];
      }
    bf16x8 pf = *(const bf16x8*)(Ps + ln * 64 + ((g * 16) ^ (((ln >> 1) & 3) << 4)));

    // O += P V
#pragma unroll
    for (int di = 0; di < 4; ++di)
      o_acc[di] = __builtin_amdgcn_mfma_f32_16x16x32_bf16(pf, vf[di], o_acc[di], 0, 0, 0);

    if (TABLE) ebc = ebn;
  }

  // reduce l over the 16 ln-lanes, normalize, store
#pragma unroll
  for (int r = 0; r < 4; ++r) {
    float rs = l_acc[r];
#pragma unroll
    for (int off = 1; off < 16; off <<= 1)
      rs += __shfl_xor(rs, off, 64);
    float inv = 1.f / rs;
    int q = q0 + g * 4 + r;
#pragma unroll
    for (int di = 0; di < 4; ++di)
      attn[((size_t)b * 1024 + q) * 512 + h * 64 + di * 16 + ln] =
          (__bf16)(o_acc[di][r] * inv);
  }
}

extern "C" void kernel_launch(void* const* d_in, const int* in_sizes, int n_in,
                              void* d_out, int out_size, void* d_ws, size_t ws_size,
                              hipStream_t stream) {
  const float* x     = (const float*)d_in[0];
  const float* gb    = (const float*)d_in[1];
  const float* w_in  = (const float*)d_in[2];
  const float* b_in  = (const float*)d_in[3];
  const float* w_out = (const float*)d_in[4];
  const float* b_out = (const float*)d_in[5];
  const float* bstr  = (const float*)d_in[6];

  char* ws = (char*)d_ws;
  __bf16* qk    = (__bf16*)(ws);                      // 16,777,216 B
  __bf16* vT    = (__bf16*)(ws + 16777216);           //  8,388,608 B
  __bf16* xb    = (__bf16*)(ws + 25165824);           //  8,388,608 B
  __bf16* w1    = (__bf16*)(ws + 33554432);           //  1,572,864 B
  __bf16* w2    = (__bf16*)(ws + 35127296);           //    524,288 B
  _Float16* ebT = (_Float16*)(ws + 35651584);         // 16,777,216 B (if fits)
  __bf16* attn_buf = xb;  // alias: x_bf16 dead after GEMM1

  const bool use_tab = ws_size >= (size_t)35651584 + 16777216;

  cvt_f32_bf16<<<2048, 256, 0, stream>>>(x, xb, (8 * 1024 * 512) / 4);
  cvt_f32_bf16<<<768, 256, 0, stream>>>(w_in, w1, (1536 * 512) / 4);
  cvt_f32_bf16<<<256, 256, 0, stream>>>(w_out, w2, (512 * 512) / 4);

  gemm_bt<1><<<dim3(12, 64), 256, 0, stream>>>(xb, w1, b_in, qk, vT, 8192, 1536, 512);
  if (use_tab) {
    build_ebias<<<4096, 256, 0, stream>>>(gb, bstr, ebT);
    attn_fused<1><<<512, 512, 0, stream>>>(qk, vT, ebT, gb, bstr, attn_buf);
  } else {
    attn_fused<0><<<512, 512, 0, stream>>>(qk, vT, ebT, gb, bstr, attn_buf);
  }
  gemm_bt<0><<<dim3(4, 64), 256, 0, stream>>>(attn_buf, w2, b_out, d_out, nullptr, 8192, 512, 512);
}